// Round 6
// baseline (3587.185 us; speedup 1.0000x reference)
//
#include <hip/hip_runtime.h>
#include <hip/hip_bf16.h>

#define HID   1000
#define DICT  4811
#define TT    44
#define BB    256
#define G4    4000
#define G4P   4096
#define K1P   2048
#define K2P   6912
#define HP    1024
#define DP    4864
#define Z2_H2 4864
#define Z2_H1 5888
#define PD    3
#define GPART ((long long)BB * G4P)

typedef __attribute__((ext_vector_type(8))) short short8;
typedef __attribute__((ext_vector_type(4))) float f32x4;

__device__ __forceinline__ short f2b(float f) {
    unsigned u = __float_as_uint(f);
    unsigned r = (u + 0x7FFFu + ((u >> 16) & 1u)) >> 16;
    return (short)r;
}

__device__ __forceinline__ void gload16(const void* g, const short* l) {
    __builtin_amdgcn_global_load_lds(
        (const __attribute__((address_space(1))) unsigned int*)g,
        (__attribute__((address_space(3))) unsigned int*)l, 16, 0, 0);
}

// ---------------- prep kernels ----------------
__global__ void prep_w1p(const float* __restrict__ wih1, const float* __restrict__ whh1,
                         short* __restrict__ w) {
    for (size_t i = (size_t)blockIdx.x * blockDim.x + threadIdx.x; i < (size_t)G4P * K1P;
         i += (size_t)gridDim.x * blockDim.x) {
        int n = (int)(i >> 11), j = (int)(i & 2047);
        float v = 0.f;
        if (n < G4) {
            if (j < HID) v = wih1[(size_t)n * 2000 + j];
            else if (j >= 1024 && j < 1024 + HID) {
                int jj = j - 1024;
                v = wih1[(size_t)n * 2000 + HID + jj] + whh1[(size_t)n * HID + jj];
            }
        }
        w[i] = f2b(v);
    }
}

__global__ void prep_w2p(const float* __restrict__ wih2, const float* __restrict__ whh2,
                         short* __restrict__ w) {
    int n = blockIdx.y;
    int j = blockIdx.x * 256 + threadIdx.x;
    float v = 0.f;
    if (n < G4) {
        if (j < DICT) v = wih2[(size_t)n * 6811 + j];
        else if (j >= Z2_H2 && j < Z2_H2 + HID) {
            int jj = j - Z2_H2;
            v = wih2[(size_t)n * 6811 + DICT + jj] + whh2[(size_t)n * HID + jj];
        } else if (j >= Z2_H1 && j < Z2_H1 + HID) {
            int jj = j - Z2_H1;
            v = wih2[(size_t)n * 6811 + DICT + HID + jj];
        }
    }
    w[(size_t)n * K2P + j] = f2b(v);
}

__global__ void prep_outwp(const float* __restrict__ outw, short* __restrict__ w) {
    int n = blockIdx.y;
    int j = blockIdx.x * 256 + threadIdx.x;
    float v = (n < DICT && j < HID) ? outw[(size_t)n * HID + j] : 0.f;
    w[(size_t)n * HP + j] = f2b(v);
}

__global__ void prep_cvt(const float* __restrict__ src, short* __restrict__ dst, size_t n) {
    for (size_t i = (size_t)blockIdx.x * blockDim.x + threadIdx.x; i < n;
         i += (size_t)gridDim.x * blockDim.x)
        dst[i] = f2b(src[i]);
}

__global__ void prep_addv(const float* __restrict__ a, const float* __restrict__ b,
                          float* __restrict__ dst, int n) {
    int i = blockIdx.x * blockDim.x + threadIdx.x;
    if (i < n) dst[i] = a[i] + b[i];
}

__global__ void init_vec(const float* __restrict__ src, short* __restrict__ dst, int ld) {
    int i = blockIdx.x * blockDim.x + threadIdx.x;
    if (i >= BB * HID) return;
    int b = i / HID, h = i % HID;
    dst[(size_t)b * ld + h] = f2b(src[i]);
}

// ---------------- xp projection GEMM (round-3 verified kernel, EPI=1/AF32=1) ----------
template <int EPI, int AF32>
__global__ __launch_bounds__(256) void gemm_nt(
    const void* __restrict__ Ap, int lda,
    const short* __restrict__ Bp, int ldb,
    const float* __restrict__ bias,
    void* __restrict__ Cp, long long partStride, int ldc,
    int M, int N, int Kvalid)
{
    __shared__ short As[64][40];
    __shared__ short Bs[64][40];
    const int tid  = threadIdx.x;
    const int lane = tid & 63;
    const int wave = tid >> 6;
    const int wm = wave >> 1, wn = wave & 1;
    const int tm = blockIdx.y * 64, tn = blockIdx.x * 64;
    const int srow = tid >> 2;
    const int scol = (tid & 3) * 8;

    const int nk = (Kvalid + 31) >> 5;
    const int s0 = (int)(((long long)nk * blockIdx.z) / gridDim.z);
    const int s1 = (int)(((long long)nk * (blockIdx.z + 1)) / gridDim.z);

    const int arow = tm + srow;
    const int brow = tn + srow;
    const bool bvalid = brow < N;

    auto loadA = [&](int ks) -> short8 {
        int k = (ks << 5) + scol;
        short8 r = {0, 0, 0, 0, 0, 0, 0, 0};
        if (k + 8 <= Kvalid) {
            if (AF32) {
                const f32x4* p = (const f32x4*)((const float*)Ap + (size_t)arow * lda + k);
                f32x4 u0 = p[0], u1 = p[1];
                r[0] = f2b(u0[0]); r[1] = f2b(u0[1]); r[2] = f2b(u0[2]); r[3] = f2b(u0[3]);
                r[4] = f2b(u1[0]); r[5] = f2b(u1[1]); r[6] = f2b(u1[2]); r[7] = f2b(u1[3]);
            } else {
                r = *(const short8*)((const short*)Ap + (size_t)arow * lda + k);
            }
        }
        return r;
    };
    auto loadB = [&](int ks) -> short8 {
        int k = (ks << 5) + scol;
        short8 r = {0, 0, 0, 0, 0, 0, 0, 0};
        if (bvalid && (k + 8 <= Kvalid))
            r = *(const short8*)(Bp + (size_t)brow * ldb + k);
        return r;
    };

    f32x4 acc[2][2];
    for (int a = 0; a < 2; ++a)
        for (int b = 0; b < 2; ++b)
            acc[a][b] = (f32x4){0.f, 0.f, 0.f, 0.f};

    short8 ra = loadA(s0), rb = loadB(s0);
    *(short8*)&As[srow][scol] = ra;
    *(short8*)&Bs[srow][scol] = rb;
    __syncthreads();

    const int kg = (lane >> 4) * 8;
    const int fr = lane & 15;

    for (int s = s0; s < s1; ++s) {
        short8 a0 = *(short8*)&As[wm * 32 + fr][kg];
        short8 a1 = *(short8*)&As[wm * 32 + 16 + fr][kg];
        short8 b0 = *(short8*)&Bs[wn * 32 + fr][kg];
        short8 b1 = *(short8*)&Bs[wn * 32 + 16 + fr][kg];
        short8 na, nb;
        if (s + 1 < s1) { na = loadA(s + 1); nb = loadB(s + 1); }
        acc[0][0] = __builtin_amdgcn_mfma_f32_16x16x32_bf16(a0, b0, acc[0][0], 0, 0, 0);
        acc[0][1] = __builtin_amdgcn_mfma_f32_16x16x32_bf16(a0, b1, acc[0][1], 0, 0, 0);
        acc[1][0] = __builtin_amdgcn_mfma_f32_16x16x32_bf16(a1, b0, acc[1][0], 0, 0, 0);
        acc[1][1] = __builtin_amdgcn_mfma_f32_16x16x32_bf16(a1, b1, acc[1][1], 0, 0, 0);
        __syncthreads();
        if (s + 1 < s1) {
            *(short8*)&As[srow][scol] = na;
            *(short8*)&Bs[srow][scol] = nb;
        }
        __syncthreads();
    }

    float* Cf = (float*)Cp + (size_t)partStride * blockIdx.z;
    for (int mi = 0; mi < 2; ++mi)
        for (int ni = 0; ni < 2; ++ni) {
            int col = tn + wn * 32 + ni * 16 + (lane & 15);
            if (col >= N) continue;
            float bv = bias ? bias[col] : 0.f;
            int row0 = tm + wm * 32 + mi * 16 + ((lane >> 4) << 2);
            f32x4 v = acc[mi][ni];
            for (int j = 0; j < 4; ++j) {
                int row = row0 + j;
                float val = v[j] + bv;
                if (EPI == 0) {
                    Cf[(size_t)row * ldc + col] = val;
                } else {
                    int b = row / TT, t = row % TT;
                    ((short*)Cp)[((size_t)t * BB + b) * ldc + col] = f2b(val);
                }
            }
        }
}

// ---------------- step GEMM v3 (round-3 verified): C[256,N] = A[256,K] * B[N,K]^T ------
__global__ __launch_bounds__(512) void gemm_step3(
    const short* __restrict__ A0, const short* __restrict__ A1, int splitA, int lda,
    const short* __restrict__ Bw, int ldb,
    float* __restrict__ C, long long partStride, int ldc, int nk)
{
    __shared__ __align__(16) short smem[PD][12288];
    const int tid  = threadIdx.x;
    const int lane = tid & 63;
    const int w    = tid >> 6;
    const int wm = w >> 1, wn = w & 1;
    const int tn = blockIdx.x * 128;
    const int s0 = (int)(((long long)nk * blockIdx.z) / gridDim.z);
    const int s1 = (int)(((long long)nk * (blockIdx.z + 1)) / gridDim.z);

    const int cA0 = w * 64 + lane;
    const int cA1 = cA0 + 512;
    const int rA0 = cA0 >> 2, rA1 = cA1 >> 2;
    const size_t aoff0 = (size_t)rA0 * lda + (size_t)((((cA0 & 3) ^ ((rA0 >> 1) & 3))) << 3);
    const size_t aoff1 = (size_t)rA1 * lda + (size_t)((((cA1 & 3) ^ ((rA1 >> 1) & 3))) << 3);
    const int cB = w * 64 + lane;
    const int rB = cB >> 2;
    const size_t boff = (size_t)(tn + rB) * ldb + (size_t)((((cB & 3) ^ ((rB >> 1) & 3))) << 3);

    auto stage = [&](int buf, int s) {
        const int k0 = s << 5;
        const short* As = (k0 < splitA) ? A0 : A1;
        const short* l = &smem[buf][0];
        gload16(As + k0 + aoff0, l + w * 512);
        gload16(As + k0 + aoff1, l + 4096 + w * 512);
        gload16(Bw + k0 + boff,  l + 8192 + w * 512);
    };

    const int fr = lane & 15;
    const int kg = lane >> 4;
    int aRd[4], bRd[4];
    #pragma unroll
    for (int mi = 0; mi < 4; ++mi) {
        int row = wm * 64 + mi * 16 + fr;
        aRd[mi] = row * 32 + ((kg ^ ((row >> 1) & 3)) << 3);
    }
    #pragma unroll
    for (int ni = 0; ni < 4; ++ni) {
        int row = wn * 64 + ni * 16 + fr;
        bRd[ni] = 8192 + row * 32 + ((kg ^ ((row >> 1) & 3)) << 3);
    }

    f32x4 acc[4][4];
    #pragma unroll
    for (int a = 0; a < 4; ++a)
        #pragma unroll
        for (int b = 0; b < 4; ++b)
            acc[a][b] = (f32x4){0.f, 0.f, 0.f, 0.f};

    #pragma unroll
    for (int i = 0; i < PD; ++i)
        if (s0 + i < s1) stage(i, s0 + i);

    int buf = 0;
    for (int s = s0; s < s1; ++s) {
        const int ahead = s1 - 1 - s;
        if (ahead >= 2)      asm volatile("s_waitcnt vmcnt(6)" ::: "memory");
        else if (ahead == 1) asm volatile("s_waitcnt vmcnt(3)" ::: "memory");
        else                 asm volatile("s_waitcnt vmcnt(0)" ::: "memory");
        __builtin_amdgcn_s_barrier();

        const short* bp = &smem[buf][0];
        short8 af[4], bf[4];
        #pragma unroll
        for (int i = 0; i < 4; ++i) af[i] = *(const short8*)(bp + aRd[i]);
        #pragma unroll
        for (int i = 0; i < 4; ++i) bf[i] = *(const short8*)(bp + bRd[i]);
        asm volatile("s_waitcnt lgkmcnt(0)" ::: "memory");
        __builtin_amdgcn_sched_barrier(0);
        __builtin_amdgcn_s_barrier();
        if (s + PD < s1) stage(buf, s + PD);

        #pragma unroll
        for (int mi = 0; mi < 4; ++mi)
            #pragma unroll
            for (int ni = 0; ni < 4; ++ni)
                acc[mi][ni] = __builtin_amdgcn_mfma_f32_16x16x32_bf16(af[mi], bf[ni], acc[mi][ni], 0, 0, 0);

        buf = (buf + 1 == PD) ? 0 : buf + 1;
    }

    float* Cp = C + (size_t)partStride * blockIdx.z;
    const int colb = tn + wn * 64 + fr;
    const int rowb = wm * 64 + (kg << 2);
    #pragma unroll
    for (int mi = 0; mi < 4; ++mi)
        #pragma unroll
        for (int ni = 0; ni < 4; ++ni) {
            int col = colb + ni * 16;
            int row0 = rowb + mi * 16;
            #pragma unroll
            for (int j = 0; j < 4; ++j)
                Cp[(size_t)(row0 + j) * ldc + col] = acc[mi][ni][j];
        }
}

// ---------------- NEW THIS ROUND: logits GEMM + batch-axis softmax, fused -------------
// block: cols [bx*64, +64), full M=256 (= full batch), K=1024, splitK=1.
// 8 waves: wm=w>>1 (64-row band), wn=w&1 (32-col band); wave-tile 64x32.
__global__ __launch_bounds__(512) void logits_sm(
    const short* __restrict__ A /*h2pad*/, const short* __restrict__ Bw /*outwb*/,
    const float* __restrict__ outb, float* __restrict__ out,
    short* __restrict__ z2, int t)
{
    __shared__ __align__(16) short smem[PD][10240];   // A 8192 | B 2048 shorts per buf
    __shared__ float red[256];
    const int tid  = threadIdx.x;
    const int lane = tid & 63;
    const int w    = tid >> 6;
    const int wm = w >> 1, wn = w & 1;
    const int tn = blockIdx.x * 64;
    const int nk = HP / 32;                        // 32

    const int cA0 = w * 64 + lane;
    const int cA1 = cA0 + 512;
    const int rA0 = cA0 >> 2, rA1 = cA1 >> 2;
    const size_t aoff0 = (size_t)rA0 * HP + (size_t)((((cA0 & 3) ^ ((rA0 >> 1) & 3))) << 3);
    const size_t aoff1 = (size_t)rA1 * HP + (size_t)((((cA1 & 3) ^ ((rA1 >> 1) & 3))) << 3);
    const int cB = w * 32 + (lane & 31);           // 256 B-chunks: 64 rows x 4
    const int rB = cB >> 2;
    const size_t boff = (size_t)(tn + rB) * HP + (size_t)((((cB & 3) ^ ((rB >> 1) & 3))) << 3);

    auto stage = [&](int buf, int s) {
        const int k0 = s << 5;
        const short* l = &smem[buf][0];
        gload16(A + k0 + aoff0, l + w * 512);
        gload16(A + k0 + aoff1, l + 4096 + w * 512);
        if (lane < 32) gload16(Bw + k0 + boff, l + 8192 + w * 256);
    };

    const int fr = lane & 15;
    const int kg = lane >> 4;
    int aRd[4], bRd[2];
    #pragma unroll
    for (int mi = 0; mi < 4; ++mi) {
        int row = wm * 64 + mi * 16 + fr;
        aRd[mi] = row * 32 + ((kg ^ ((row >> 1) & 3)) << 3);
    }
    #pragma unroll
    for (int ni = 0; ni < 2; ++ni) {
        int row = wn * 32 + ni * 16 + fr;
        bRd[ni] = 8192 + row * 32 + ((kg ^ ((row >> 1) & 3)) << 3);
    }

    f32x4 acc[4][2];
    #pragma unroll
    for (int a = 0; a < 4; ++a)
        #pragma unroll
        for (int b = 0; b < 2; ++b)
            acc[a][b] = (f32x4){0.f, 0.f, 0.f, 0.f};

    #pragma unroll
    for (int i = 0; i < PD; ++i) stage(i, i);

    int buf = 0;
    for (int s = 0; s < nk; ++s) {
        const int ahead = nk - 1 - s;
        if (ahead >= 2)      asm volatile("s_waitcnt vmcnt(6)" ::: "memory");
        else if (ahead == 1) asm volatile("s_waitcnt vmcnt(3)" ::: "memory");
        else                 asm volatile("s_waitcnt vmcnt(0)" ::: "memory");
        __builtin_amdgcn_s_barrier();

        const short* bp = &smem[buf][0];
        short8 af[4], bf[2];
        #pragma unroll
        for (int i = 0; i < 4; ++i) af[i] = *(const short8*)(bp + aRd[i]);
        #pragma unroll
        for (int i = 0; i < 2; ++i) bf[i] = *(const short8*)(bp + bRd[i]);
        asm volatile("s_waitcnt lgkmcnt(0)" ::: "memory");
        __builtin_amdgcn_sched_barrier(0);
        __builtin_amdgcn_s_barrier();
        if (s + PD < nk) stage(buf, s + PD);

        #pragma unroll
        for (int mi = 0; mi < 4; ++mi)
            #pragma unroll
            for (int ni = 0; ni < 2; ++ni)
                acc[mi][ni] = __builtin_amdgcn_mfma_f32_16x16x32_bf16(af[mi], bf[ni], acc[mi][ni], 0, 0, 0);

        buf = (buf + 1 == PD) ? 0 : buf + 1;
    }

    // ---- epilogue: bias + softmax over the 256 batch rows per column ----
    int   colv[2];
    float bv[2];
    #pragma unroll
    for (int ni = 0; ni < 2; ++ni) {
        colv[ni] = tn + wn * 32 + ni * 16 + fr;
        bv[ni] = (colv[ni] < DICT) ? outb[colv[ni]] : 0.f;
    }
    float v[4][2][4];
    float mx[2] = {-3e38f, -3e38f};
    #pragma unroll
    for (int mi = 0; mi < 4; ++mi)
        #pragma unroll
        for (int ni = 0; ni < 2; ++ni)
            #pragma unroll
            for (int j = 0; j < 4; ++j) {
                float x = acc[mi][ni][j] + bv[ni];
                v[mi][ni][j] = x;
                mx[ni] = fmaxf(mx[ni], x);
            }
    #pragma unroll
    for (int ni = 0; ni < 2; ++ni) {
        mx[ni] = fmaxf(mx[ni], __shfl_xor(mx[ni], 16));
        mx[ni] = fmaxf(mx[ni], __shfl_xor(mx[ni], 32));
    }
    if (lane < 16) {
        red[wm * 64 + wn * 32 + fr]      = mx[0];
        red[wm * 64 + wn * 32 + 16 + fr] = mx[1];
    }
    __syncthreads();
    float m[2];
    #pragma unroll
    for (int ni = 0; ni < 2; ++ni) {
        int c = wn * 32 + ni * 16 + fr;
        m[ni] = fmaxf(fmaxf(red[c], red[64 + c]), fmaxf(red[128 + c], red[192 + c]));
    }
    __syncthreads();
    float s2[2] = {0.f, 0.f};
    #pragma unroll
    for (int mi = 0; mi < 4; ++mi)
        #pragma unroll
        for (int ni = 0; ni < 2; ++ni)
            #pragma unroll
            for (int j = 0; j < 4; ++j) {
                float e = expf(v[mi][ni][j] - m[ni]);
                v[mi][ni][j] = e;
                s2[ni] += e;
            }
    #pragma unroll
    for (int ni = 0; ni < 2; ++ni) {
        s2[ni] += __shfl_xor(s2[ni], 16);
        s2[ni] += __shfl_xor(s2[ni], 32);
    }
    if (lane < 16) {
        red[wm * 64 + wn * 32 + fr]      = s2[0];
        red[wm * 64 + wn * 32 + 16 + fr] = s2[1];
    }
    __syncthreads();
    float inv[2];
    #pragma unroll
    for (int ni = 0; ni < 2; ++ni) {
        int c = wn * 32 + ni * 16 + fr;
        inv[ni] = 1.f / (red[c] + red[64 + c] + red[128 + c] + red[192 + c]);
    }
    const int rowb = wm * 64 + (kg << 2);
    #pragma unroll
    for (int mi = 0; mi < 4; ++mi)
        #pragma unroll
        for (int j = 0; j < 4; ++j) {
            int b = rowb + mi * 16 + j;
            #pragma unroll
            for (int ni = 0; ni < 2; ++ni) {
                if (colv[ni] < DICT) {
                    float y = v[mi][ni][j] * inv[ni];
                    out[(size_t)b * ((size_t)TT * DICT) + (size_t)t * DICT + colv[ni]] = y;
                    z2[(size_t)b * K2P + colv[ni]] = f2b(y);
                }
            }
        }
}

// ---------------- LSTM elementwise (round-3 verified): sum NP K-split parts ----------
template <int NP>
__global__ void lstm_ewN(const float* __restrict__ g, long long ps,
                         const float* __restrict__ bias, float* __restrict__ c,
                         short* __restrict__ d1, int ld1,
                         short* __restrict__ d2, int ld2)
{
    int i = blockIdx.x * blockDim.x + threadIdx.x;
    if (i >= BB * HID) return;
    int b = i / HID, h = i % HID;
    size_t base = (size_t)b * G4P + h;
    float gi = bias[h], gf = bias[HID + h], gg = bias[2 * HID + h], go = bias[3 * HID + h];
    #pragma unroll
    for (int p = 0; p < NP; ++p) {
        const float* gp = g + (size_t)ps * p + base;
        gi += gp[0];
        gf += gp[HID];
        gg += gp[2 * HID];
        go += gp[3 * HID];
    }
    float ii = 1.f / (1.f + expf(-gi));
    float ff = 1.f / (1.f + expf(-gf));
    float tg = tanhf(gg);
    float oo = 1.f / (1.f + expf(-go));
    float cn = ff * c[i] + ii * tg;
    c[i] = cn;
    float hn = oo * tanhf(cn);
    short hb = f2b(hn);
    d1[(size_t)b * ld1 + h] = hb;
    d2[(size_t)b * ld2 + h] = hb;
}

// ---------------- host ----------------
extern "C" void kernel_launch(void* const* d_in, const int* in_sizes, int n_in,
                              void* d_out, int out_size, void* d_ws, size_t ws_size,
                              hipStream_t stream)
{
    const float* x    = (const float*)d_in[0];
    const float* h1   = (const float*)d_in[1];
    const float* h2   = (const float*)d_in[2];
    const float* c1in = (const float*)d_in[3];
    const float* c2in = (const float*)d_in[4];
    const float* layW = (const float*)d_in[5];
    const float* layb = (const float*)d_in[6];
    const float* Wih1 = (const float*)d_in[7];
    const float* Whh1 = (const float*)d_in[8];
    const float* bih1 = (const float*)d_in[9];
    const float* bhh1 = (const float*)d_in[10];
    const float* Wih2 = (const float*)d_in[11];
    const float* Whh2 = (const float*)d_in[12];
    const float* bih2 = (const float*)d_in[13];
    const float* bhh2 = (const float*)d_in[14];
    const float* outW = (const float*)d_in[15];
    const float* outb = (const float*)d_in[16];
    float* out = (float*)d_out;
    (void)in_sizes; (void)n_in; (void)out_size; (void)ws_size;

    char* ws = (char*)d_ws;
    size_t off = 0;
    auto alloc = [&](size_t bytes) -> void* {
        size_t p = off;
        off = (off + bytes + 255) & ~(size_t)255;
        return (void*)(ws + p);
    };

    short* w1cat = (short*)alloc((size_t)G4P * K1P * 2);
    short* w2cat = (short*)alloc((size_t)G4P * K2P * 2);
    short* outwb = (short*)alloc((size_t)DP * HP * 2);
    short* laywb = (short*)alloc((size_t)HID * HID * 2);
    short* xp    = (short*)alloc((size_t)TT * BB * HP * 2);
    short* h1pad = (short*)alloc((size_t)BB * HP * 2);
    short* h2pad = (short*)alloc((size_t)BB * HP * 2);
    short* z2    = (short*)alloc((size_t)BB * K2P * 2);
    float* gbuf  = (float*)alloc((size_t)8 * BB * G4P * 4);
    float* c1    = (float*)alloc((size_t)BB * HID * 4);
    float* c2    = (float*)alloc((size_t)BB * HID * 4);
    float* bias1 = (float*)alloc((size_t)G4 * 4);
    float* bias2 = (float*)alloc((size_t)G4 * 4);

    hipMemsetAsync(xp, 0, (size_t)TT * BB * HP * 2, stream);
    hipMemsetAsync(z2, 0, (size_t)BB * K2P * 2, stream);
    hipMemsetAsync(h1pad, 0, (size_t)BB * HP * 2, stream);
    hipMemsetAsync(h2pad, 0, (size_t)BB * HP * 2, stream);

    prep_w1p<<<4096, 256, 0, stream>>>(Wih1, Whh1, w1cat);
    prep_w2p<<<dim3(27, G4P), 256, 0, stream>>>(Wih2, Whh2, w2cat);
    prep_outwp<<<dim3(4, DP), 256, 0, stream>>>(outW, outwb);
    prep_cvt<<<1024, 256, 0, stream>>>(layW, laywb, (size_t)HID * HID);
    prep_addv<<<16, 256, 0, stream>>>(bih1, bhh1, bias1, G4);
    prep_addv<<<16, 256, 0, stream>>>(bih2, bhh2, bias2, G4);
    init_vec<<<1000, 256, 0, stream>>>(h1, h1pad, HP);
    init_vec<<<1000, 256, 0, stream>>>(h2, h2pad, HP);
    init_vec<<<1000, 256, 0, stream>>>(h2, z2 + Z2_H2, K2P);
    hipMemcpyAsync(c1, c1in, (size_t)BB * HID * 4, hipMemcpyDeviceToDevice, stream);
    hipMemcpyAsync(c2, c2in, (size_t)BB * HID * 4, hipMemcpyDeviceToDevice, stream);

    // input projection -> xp[t][b][0:1000] (bf16, stride 1024, pads stay zero)
    gemm_nt<1, 1><<<dim3(16, (BB * TT) / 64, 1), 256, 0, stream>>>(
        x, HID, laywb, HID, layb, xp, 0, HP, BB * TT, HID, HID);

    for (int t = 0; t < TT; ++t) {
        // gates1 = [xp_t | h1] @ w1cat^T   (K-split 4)
        gemm_step3<<<dim3(32, 1, 4), 512, 0, stream>>>(
            xp + (size_t)t * BB * HP, h1pad - HP, 1024, HP, w1cat, K1P, gbuf, GPART, G4P, K1P / 32);
        lstm_ewN<4><<<1000, 256, 0, stream>>>(gbuf, GPART, bias1, c1, z2 + Z2_H1, K2P, h1pad, HP);

        // gates2 = z2 @ w2cat^T   (K-split 8)
        gemm_step3<<<dim3(32, 1, 8), 512, 0, stream>>>(
            z2, z2, 0, K2P, w2cat, K2P, gbuf, GPART, G4P, K2P / 32);
        lstm_ewN<8><<<1000, 256, 0, stream>>>(gbuf, GPART, bias2, c2, z2 + Z2_H2, K2P, h2pad, HP);

        // logits(t) + batch-softmax fused -> out, z2.prev
        logits_sm<<<76, 512, 0, stream>>>(h2pad, outwb, outb, out, z2, t);
    }
}

// Round 7
// 3428.343 us; speedup vs baseline: 1.0463x; 1.0463x over previous
//
#include <hip/hip_runtime.h>
#include <hip/hip_bf16.h>

#define HID   1000
#define DICT  4811
#define TT    44
#define BB    256
#define G4    4000
#define G4P   4096
#define K1P   2048
#define K2P   6912
#define HP    1024
#define DP    4864
#define Z2_H2 4864
#define Z2_H1 5888
#define PD    3
#define GPART ((long long)BB * G4P)

typedef __attribute__((ext_vector_type(8))) short short8;
typedef __attribute__((ext_vector_type(4))) float f32x4;

__device__ __forceinline__ short f2b(float f) {
    unsigned u = __float_as_uint(f);
    unsigned r = (u + 0x7FFFu + ((u >> 16) & 1u)) >> 16;
    return (short)r;
}

__device__ __forceinline__ void gload16(const void* g, const short* l) {
    __builtin_amdgcn_global_load_lds(
        (const __attribute__((address_space(1))) unsigned int*)g,
        (__attribute__((address_space(3))) unsigned int*)l, 16, 0, 0);
}

// ---------------- prep kernels ----------------
__global__ void prep_w1p(const float* __restrict__ wih1, const float* __restrict__ whh1,
                         short* __restrict__ w) {
    for (size_t i = (size_t)blockIdx.x * blockDim.x + threadIdx.x; i < (size_t)G4P * K1P;
         i += (size_t)gridDim.x * blockDim.x) {
        int n = (int)(i >> 11), j = (int)(i & 2047);
        float v = 0.f;
        if (n < G4) {
            if (j < HID) v = wih1[(size_t)n * 2000 + j];
            else if (j >= 1024 && j < 1024 + HID) {
                int jj = j - 1024;
                v = wih1[(size_t)n * 2000 + HID + jj] + whh1[(size_t)n * HID + jj];
            }
        }
        w[i] = f2b(v);
    }
}

__global__ void prep_w2p(const float* __restrict__ wih2, const float* __restrict__ whh2,
                         short* __restrict__ w) {
    int n = blockIdx.y;
    int j = blockIdx.x * 256 + threadIdx.x;
    float v = 0.f;
    if (n < G4) {
        if (j < DICT) v = wih2[(size_t)n * 6811 + j];
        else if (j >= Z2_H2 && j < Z2_H2 + HID) {
            int jj = j - Z2_H2;
            v = wih2[(size_t)n * 6811 + DICT + jj] + whh2[(size_t)n * HID + jj];
        } else if (j >= Z2_H1 && j < Z2_H1 + HID) {
            int jj = j - Z2_H1;
            v = wih2[(size_t)n * 6811 + DICT + HID + jj];
        }
    }
    w[(size_t)n * K2P + j] = f2b(v);
}

__global__ void prep_outwp(const float* __restrict__ outw, short* __restrict__ w) {
    int n = blockIdx.y;
    int j = blockIdx.x * 256 + threadIdx.x;
    float v = (n < DICT && j < HID) ? outw[(size_t)n * HID + j] : 0.f;
    w[(size_t)n * HP + j] = f2b(v);
}

__global__ void prep_cvt(const float* __restrict__ src, short* __restrict__ dst, size_t n) {
    for (size_t i = (size_t)blockIdx.x * blockDim.x + threadIdx.x; i < n;
         i += (size_t)gridDim.x * blockDim.x)
        dst[i] = f2b(src[i]);
}

__global__ void prep_addv(const float* __restrict__ a, const float* __restrict__ b,
                          float* __restrict__ dst, int n) {
    int i = blockIdx.x * blockDim.x + threadIdx.x;
    if (i < n) dst[i] = a[i] + b[i];
}

__global__ void init_vec(const float* __restrict__ src, short* __restrict__ dst, int ld) {
    int i = blockIdx.x * blockDim.x + threadIdx.x;
    if (i >= BB * HID) return;
    int b = i / HID, h = i % HID;
    dst[(size_t)b * ld + h] = f2b(src[i]);
}

// ---------------- xp projection GEMM (round-3 verified kernel, EPI=1/AF32=1) ----------
template <int EPI, int AF32>
__global__ __launch_bounds__(256) void gemm_nt(
    const void* __restrict__ Ap, int lda,
    const short* __restrict__ Bp, int ldb,
    const float* __restrict__ bias,
    void* __restrict__ Cp, long long partStride, int ldc,
    int M, int N, int Kvalid)
{
    __shared__ short As[64][40];
    __shared__ short Bs[64][40];
    const int tid  = threadIdx.x;
    const int lane = tid & 63;
    const int wave = tid >> 6;
    const int wm = wave >> 1, wn = wave & 1;
    const int tm = blockIdx.y * 64, tn = blockIdx.x * 64;
    const int srow = tid >> 2;
    const int scol = (tid & 3) * 8;

    const int nk = (Kvalid + 31) >> 5;
    const int s0 = (int)(((long long)nk * blockIdx.z) / gridDim.z);
    const int s1 = (int)(((long long)nk * (blockIdx.z + 1)) / gridDim.z);

    const int arow = tm + srow;
    const int brow = tn + srow;
    const bool bvalid = brow < N;

    auto loadA = [&](int ks) -> short8 {
        int k = (ks << 5) + scol;
        short8 r = {0, 0, 0, 0, 0, 0, 0, 0};
        if (k + 8 <= Kvalid) {
            if (AF32) {
                const f32x4* p = (const f32x4*)((const float*)Ap + (size_t)arow * lda + k);
                f32x4 u0 = p[0], u1 = p[1];
                r[0] = f2b(u0[0]); r[1] = f2b(u0[1]); r[2] = f2b(u0[2]); r[3] = f2b(u0[3]);
                r[4] = f2b(u1[0]); r[5] = f2b(u1[1]); r[6] = f2b(u1[2]); r[7] = f2b(u1[3]);
            } else {
                r = *(const short8*)((const short*)Ap + (size_t)arow * lda + k);
            }
        }
        return r;
    };
    auto loadB = [&](int ks) -> short8 {
        int k = (ks << 5) + scol;
        short8 r = {0, 0, 0, 0, 0, 0, 0, 0};
        if (bvalid && (k + 8 <= Kvalid))
            r = *(const short8*)(Bp + (size_t)brow * ldb + k);
        return r;
    };

    f32x4 acc[2][2];
    for (int a = 0; a < 2; ++a)
        for (int b = 0; b < 2; ++b)
            acc[a][b] = (f32x4){0.f, 0.f, 0.f, 0.f};

    short8 ra = loadA(s0), rb = loadB(s0);
    *(short8*)&As[srow][scol] = ra;
    *(short8*)&Bs[srow][scol] = rb;
    __syncthreads();

    const int kg = (lane >> 4) * 8;
    const int fr = lane & 15;

    for (int s = s0; s < s1; ++s) {
        short8 a0 = *(short8*)&As[wm * 32 + fr][kg];
        short8 a1 = *(short8*)&As[wm * 32 + 16 + fr][kg];
        short8 b0 = *(short8*)&Bs[wn * 32 + fr][kg];
        short8 b1 = *(short8*)&Bs[wn * 32 + 16 + fr][kg];
        short8 na, nb;
        if (s + 1 < s1) { na = loadA(s + 1); nb = loadB(s + 1); }
        acc[0][0] = __builtin_amdgcn_mfma_f32_16x16x32_bf16(a0, b0, acc[0][0], 0, 0, 0);
        acc[0][1] = __builtin_amdgcn_mfma_f32_16x16x32_bf16(a0, b1, acc[0][1], 0, 0, 0);
        acc[1][0] = __builtin_amdgcn_mfma_f32_16x16x32_bf16(a1, b0, acc[1][0], 0, 0, 0);
        acc[1][1] = __builtin_amdgcn_mfma_f32_16x16x32_bf16(a1, b1, acc[1][1], 0, 0, 0);
        __syncthreads();
        if (s + 1 < s1) {
            *(short8*)&As[srow][scol] = na;
            *(short8*)&Bs[srow][scol] = nb;
        }
        __syncthreads();
    }

    float* Cf = (float*)Cp + (size_t)partStride * blockIdx.z;
    for (int mi = 0; mi < 2; ++mi)
        for (int ni = 0; ni < 2; ++ni) {
            int col = tn + wn * 32 + ni * 16 + (lane & 15);
            if (col >= N) continue;
            float bv = bias ? bias[col] : 0.f;
            int row0 = tm + wm * 32 + mi * 16 + ((lane >> 4) << 2);
            f32x4 v = acc[mi][ni];
            for (int j = 0; j < 4; ++j) {
                int row = row0 + j;
                float val = v[j] + bv;
                if (EPI == 0) {
                    Cf[(size_t)row * ldc + col] = val;
                } else {
                    int b = row / TT, t = row % TT;
                    ((short*)Cp)[((size_t)t * BB + b) * ldc + col] = f2b(val);
                }
            }
        }
}

// ---------------- NEW: step GEMM, 128x128 tile, 2 blocks/CU ----------------
// C[256,N] = A[256,K] * B[N,K]^T. 512 threads = 8 waves (2M x 4N, wave-tile
// 64x32, acc[4][2] ~90 VGPR). LDS 16KB/stage x PD=3 = 48KB -> with
// __launch_bounds__(512,4) two blocks co-reside per CU (96KB LDS, <=128 VGPR)
// so barrier/vmcnt stalls of one block are hidden by the other.
// Staging: 2 global_load_lds per thread per stage (A chunk tid, B chunk tid),
// XOR bank swizzle applied on global source & LDS read (both-sides, rule 21).
__global__ __launch_bounds__(512, 4) void gemm_s128(
    const short* __restrict__ A0, const short* __restrict__ A1, int splitA, int lda,
    const short* __restrict__ Bw, int ldb,
    float* __restrict__ C, long long partStride, int ldc, int nk)
{
    __shared__ __align__(16) short smem[PD][8192];   // per buf: A 4096 sh | B 4096 sh
    const int tid  = threadIdx.x;
    const int lane = tid & 63;
    const int w    = tid >> 6;
    const int wm = w >> 2, wn = w & 3;
    const int tm = blockIdx.y * 128;
    const int tn = blockIdx.x * 128;
    const int s0 = (int)(((long long)nk * blockIdx.z) / gridDim.z);
    const int s1 = (int)(((long long)nk * (blockIdx.z + 1)) / gridDim.z);

    // staging: 512 chunks (128 rows x 4 slots) each for A and B; thread stages chunk tid
    const int rA = tid >> 2, slA = tid & 3;
    const int swz = (slA ^ ((rA >> 1) & 3)) << 3;    // swizzled k-offset (shorts)
    const size_t aoff = (size_t)(tm + rA) * lda + (size_t)swz;
    const size_t boff = (size_t)(tn + rA) * ldb + (size_t)swz;

    auto stage = [&](int buf, int s) {
        const int k0 = s << 5;
        const short* As = (k0 < splitA) ? A0 : A1;
        const short* l = &smem[buf][0];
        gload16(As + k0 + aoff, l + tid * 8);          // dest = base + lane*16B (wave-uniform)
        gload16(Bw + k0 + boff, l + 4096 + tid * 8);
    };

    const int fr = lane & 15;
    const int kg = lane >> 4;
    int aRd[4], bRd[2];
    #pragma unroll
    for (int mi = 0; mi < 4; ++mi) {
        int row = wm * 64 + mi * 16 + fr;
        aRd[mi] = row * 32 + ((kg ^ ((row >> 1) & 3)) << 3);
    }
    #pragma unroll
    for (int ni = 0; ni < 2; ++ni) {
        int row = wn * 32 + ni * 16 + fr;
        bRd[ni] = 4096 + row * 32 + ((kg ^ ((row >> 1) & 3)) << 3);
    }

    f32x4 acc[4][2];
    #pragma unroll
    for (int a = 0; a < 4; ++a)
        #pragma unroll
        for (int b = 0; b < 2; ++b)
            acc[a][b] = (f32x4){0.f, 0.f, 0.f, 0.f};

    #pragma unroll
    for (int i = 0; i < PD; ++i)
        if (s0 + i < s1) stage(i, s0 + i);

    int buf = 0;
    for (int s = s0; s < s1; ++s) {
        const int ahead = s1 - 1 - s;                 // stages issued beyond s (2 loads each)
        if (ahead >= 2)      asm volatile("s_waitcnt vmcnt(4)" ::: "memory");
        else if (ahead == 1) asm volatile("s_waitcnt vmcnt(2)" ::: "memory");
        else                 asm volatile("s_waitcnt vmcnt(0)" ::: "memory");
        __builtin_amdgcn_s_barrier();                 // buf fully staged for all waves

        const short* bp = &smem[buf][0];
        short8 af[4], bf[2];
        #pragma unroll
        for (int i = 0; i < 4; ++i) af[i] = *(const short8*)(bp + aRd[i]);
        #pragma unroll
        for (int i = 0; i < 2; ++i) bf[i] = *(const short8*)(bp + bRd[i]);
        asm volatile("s_waitcnt lgkmcnt(0)" ::: "memory");
        __builtin_amdgcn_sched_barrier(0);            // rule 18: keep MFMAs below the wait
        __builtin_amdgcn_s_barrier();                 // all waves done reading buf
        if (s + PD < s1) stage(buf, s + PD);          // recycle buf

        #pragma unroll
        for (int mi = 0; mi < 4; ++mi)
            #pragma unroll
            for (int ni = 0; ni < 2; ++ni)
                acc[mi][ni] = __builtin_amdgcn_mfma_f32_16x16x32_bf16(af[mi], bf[ni], acc[mi][ni], 0, 0, 0);

        buf = (buf + 1 == PD) ? 0 : buf + 1;
    }

    float* Cp = C + (size_t)partStride * blockIdx.z;
    const int colb = tn + wn * 32 + fr;
    const int rowb = tm + wm * 64 + (kg << 2);
    #pragma unroll
    for (int mi = 0; mi < 4; ++mi)
        #pragma unroll
        for (int ni = 0; ni < 2; ++ni) {
            int col = colb + ni * 16;
            int row0 = rowb + mi * 16;
            #pragma unroll
            for (int j = 0; j < 4; ++j)
                Cp[(size_t)(row0 + j) * ldc + col] = acc[mi][ni][j];
        }
}

// ---------------- logits GEMM + batch-axis softmax, fused (round-6 verified) ----------
__global__ __launch_bounds__(512) void logits_sm(
    const short* __restrict__ A /*h2pad*/, const short* __restrict__ Bw /*outwb*/,
    const float* __restrict__ outb, float* __restrict__ out,
    short* __restrict__ z2, int t)
{
    __shared__ __align__(16) short smem[PD][10240];   // A 8192 | B 2048 shorts per buf
    __shared__ float red[256];
    const int tid  = threadIdx.x;
    const int lane = tid & 63;
    const int w    = tid >> 6;
    const int wm = w >> 1, wn = w & 1;
    const int tn = blockIdx.x * 64;
    const int nk = HP / 32;                        // 32

    const int cA0 = w * 64 + lane;
    const int cA1 = cA0 + 512;
    const int rA0 = cA0 >> 2, rA1 = cA1 >> 2;
    const size_t aoff0 = (size_t)rA0 * HP + (size_t)((((cA0 & 3) ^ ((rA0 >> 1) & 3))) << 3);
    const size_t aoff1 = (size_t)rA1 * HP + (size_t)((((cA1 & 3) ^ ((rA1 >> 1) & 3))) << 3);
    const int cB = w * 32 + (lane & 31);           // 256 B-chunks: 64 rows x 4
    const int rB = cB >> 2;
    const size_t boff = (size_t)(tn + rB) * HP + (size_t)((((cB & 3) ^ ((rB >> 1) & 3))) << 3);

    auto stage = [&](int buf, int s) {
        const int k0 = s << 5;
        const short* l = &smem[buf][0];
        gload16(A + k0 + aoff0, l + w * 512);
        gload16(A + k0 + aoff1, l + 4096 + w * 512);
        if (lane < 32) gload16(Bw + k0 + boff, l + 8192 + w * 256);
    };

    const int fr = lane & 15;
    const int kg = lane >> 4;
    int aRd[4], bRd[2];
    #pragma unroll
    for (int mi = 0; mi < 4; ++mi) {
        int row = wm * 64 + mi * 16 + fr;
        aRd[mi] = row * 32 + ((kg ^ ((row >> 1) & 3)) << 3);
    }
    #pragma unroll
    for (int ni = 0; ni < 2; ++ni) {
        int row = wn * 32 + ni * 16 + fr;
        bRd[ni] = 8192 + row * 32 + ((kg ^ ((row >> 1) & 3)) << 3);
    }

    f32x4 acc[4][2];
    #pragma unroll
    for (int a = 0; a < 4; ++a)
        #pragma unroll
        for (int b = 0; b < 2; ++b)
            acc[a][b] = (f32x4){0.f, 0.f, 0.f, 0.f};

    #pragma unroll
    for (int i = 0; i < PD; ++i) stage(i, i);

    int buf = 0;
    for (int s = 0; s < nk; ++s) {
        const int ahead = nk - 1 - s;
        if (ahead >= 2)      asm volatile("s_waitcnt vmcnt(6)" ::: "memory");
        else if (ahead == 1) asm volatile("s_waitcnt vmcnt(3)" ::: "memory");
        else                 asm volatile("s_waitcnt vmcnt(0)" ::: "memory");
        __builtin_amdgcn_s_barrier();

        const short* bp = &smem[buf][0];
        short8 af[4], bf[2];
        #pragma unroll
        for (int i = 0; i < 4; ++i) af[i] = *(const short8*)(bp + aRd[i]);
        #pragma unroll
        for (int i = 0; i < 2; ++i) bf[i] = *(const short8*)(bp + bRd[i]);
        asm volatile("s_waitcnt lgkmcnt(0)" ::: "memory");
        __builtin_amdgcn_sched_barrier(0);
        __builtin_amdgcn_s_barrier();
        if (s + PD < nk) stage(buf, s + PD);

        #pragma unroll
        for (int mi = 0; mi < 4; ++mi)
            #pragma unroll
            for (int ni = 0; ni < 2; ++ni)
                acc[mi][ni] = __builtin_amdgcn_mfma_f32_16x16x32_bf16(af[mi], bf[ni], acc[mi][ni], 0, 0, 0);

        buf = (buf + 1 == PD) ? 0 : buf + 1;
    }

    // ---- epilogue: bias + softmax over the 256 batch rows per column ----
    int   colv[2];
    float bv[2];
    #pragma unroll
    for (int ni = 0; ni < 2; ++ni) {
        colv[ni] = tn + wn * 32 + ni * 16 + fr;
        bv[ni] = (colv[ni] < DICT) ? outb[colv[ni]] : 0.f;
    }
    float v[4][2][4];
    float mx[2] = {-3e38f, -3e38f};
    #pragma unroll
    for (int mi = 0; mi < 4; ++mi)
        #pragma unroll
        for (int ni = 0; ni < 2; ++ni)
            #pragma unroll
            for (int j = 0; j < 4; ++j) {
                float x = acc[mi][ni][j] + bv[ni];
                v[mi][ni][j] = x;
                mx[ni] = fmaxf(mx[ni], x);
            }
    #pragma unroll
    for (int ni = 0; ni < 2; ++ni) {
        mx[ni] = fmaxf(mx[ni], __shfl_xor(mx[ni], 16));
        mx[ni] = fmaxf(mx[ni], __shfl_xor(mx[ni], 32));
    }
    if (lane < 16) {
        red[wm * 64 + wn * 32 + fr]      = mx[0];
        red[wm * 64 + wn * 32 + 16 + fr] = mx[1];
    }
    __syncthreads();
    float m[2];
    #pragma unroll
    for (int ni = 0; ni < 2; ++ni) {
        int c = wn * 32 + ni * 16 + fr;
        m[ni] = fmaxf(fmaxf(red[c], red[64 + c]), fmaxf(red[128 + c], red[192 + c]));
    }
    __syncthreads();
    float s2[2] = {0.f, 0.f};
    #pragma unroll
    for (int mi = 0; mi < 4; ++mi)
        #pragma unroll
        for (int ni = 0; ni < 2; ++ni)
            #pragma unroll
            for (int j = 0; j < 4; ++j) {
                float e = expf(v[mi][ni][j] - m[ni]);
                v[mi][ni][j] = e;
                s2[ni] += e;
            }
    #pragma unroll
    for (int ni = 0; ni < 2; ++ni) {
        s2[ni] += __shfl_xor(s2[ni], 16);
        s2[ni] += __shfl_xor(s2[ni], 32);
    }
    if (lane < 16) {
        red[wm * 64 + wn * 32 + fr]      = s2[0];
        red[wm * 64 + wn * 32 + 16 + fr] = s2[1];
    }
    __syncthreads();
    float inv[2];
    #pragma unroll
    for (int ni = 0; ni < 2; ++ni) {
        int c = wn * 32 + ni * 16 + fr;
        inv[ni] = 1.f / (red[c] + red[64 + c] + red[128 + c] + red[192 + c]);
    }
    const int rowb = wm * 64 + (kg << 2);
    #pragma unroll
    for (int mi = 0; mi < 4; ++mi)
        #pragma unroll
        for (int j = 0; j < 4; ++j) {
            int b = rowb + mi * 16 + j;
            #pragma unroll
            for (int ni = 0; ni < 2; ++ni) {
                if (colv[ni] < DICT) {
                    float y = v[mi][ni][j] * inv[ni];
                    out[(size_t)b * ((size_t)TT * DICT) + (size_t)t * DICT + colv[ni]] = y;
                    z2[(size_t)b * K2P + colv[ni]] = f2b(y);
                }
            }
        }
}

// ---------------- LSTM elementwise (round-3 verified): sum NP K-split parts ----------
template <int NP>
__global__ void lstm_ewN(const float* __restrict__ g, long long ps,
                         const float* __restrict__ bias, float* __restrict__ c,
                         short* __restrict__ d1, int ld1,
                         short* __restrict__ d2, int ld2)
{
    int i = blockIdx.x * blockDim.x + threadIdx.x;
    if (i >= BB * HID) return;
    int b = i / HID, h = i % HID;
    size_t base = (size_t)b * G4P + h;
    float gi = bias[h], gf = bias[HID + h], gg = bias[2 * HID + h], go = bias[3 * HID + h];
    #pragma unroll
    for (int p = 0; p < NP; ++p) {
        const float* gp = g + (size_t)ps * p + base;
        gi += gp[0];
        gf += gp[HID];
        gg += gp[2 * HID];
        go += gp[3 * HID];
    }
    float ii = 1.f / (1.f + expf(-gi));
    float ff = 1.f / (1.f + expf(-gf));
    float tg = tanhf(gg);
    float oo = 1.f / (1.f + expf(-go));
    float cn = ff * c[i] + ii * tg;
    c[i] = cn;
    float hn = oo * tanhf(cn);
    short hb = f2b(hn);
    d1[(size_t)b * ld1 + h] = hb;
    d2[(size_t)b * ld2 + h] = hb;
}

// ---------------- host ----------------
extern "C" void kernel_launch(void* const* d_in, const int* in_sizes, int n_in,
                              void* d_out, int out_size, void* d_ws, size_t ws_size,
                              hipStream_t stream)
{
    const float* x    = (const float*)d_in[0];
    const float* h1   = (const float*)d_in[1];
    const float* h2   = (const float*)d_in[2];
    const float* c1in = (const float*)d_in[3];
    const float* c2in = (const float*)d_in[4];
    const float* layW = (const float*)d_in[5];
    const float* layb = (const float*)d_in[6];
    const float* Wih1 = (const float*)d_in[7];
    const float* Whh1 = (const float*)d_in[8];
    const float* bih1 = (const float*)d_in[9];
    const float* bhh1 = (const float*)d_in[10];
    const float* Wih2 = (const float*)d_in[11];
    const float* Whh2 = (const float*)d_in[12];
    const float* bih2 = (const float*)d_in[13];
    const float* bhh2 = (const float*)d_in[14];
    const float* outW = (const float*)d_in[15];
    const float* outb = (const float*)d_in[16];
    float* out = (float*)d_out;
    (void)in_sizes; (void)n_in; (void)out_size; (void)ws_size;

    char* ws = (char*)d_ws;
    size_t off = 0;
    auto alloc = [&](size_t bytes) -> void* {
        size_t p = off;
        off = (off + bytes + 255) & ~(size_t)255;
        return (void*)(ws + p);
    };

    short* w1cat = (short*)alloc((size_t)G4P * K1P * 2);
    short* w2cat = (short*)alloc((size_t)G4P * K2P * 2);
    short* outwb = (short*)alloc((size_t)DP * HP * 2);
    short* laywb = (short*)alloc((size_t)HID * HID * 2);
    short* xp    = (short*)alloc((size_t)TT * BB * HP * 2);
    short* h1pad = (short*)alloc((size_t)BB * HP * 2);
    short* h2pad = (short*)alloc((size_t)BB * HP * 2);
    short* z2    = (short*)alloc((size_t)BB * K2P * 2);
    float* gbuf  = (float*)alloc((size_t)8 * BB * G4P * 4);
    float* c1    = (float*)alloc((size_t)BB * HID * 4);
    float* c2    = (float*)alloc((size_t)BB * HID * 4);
    float* bias1 = (float*)alloc((size_t)G4 * 4);
    float* bias2 = (float*)alloc((size_t)G4 * 4);

    hipMemsetAsync(xp, 0, (size_t)TT * BB * HP * 2, stream);
    hipMemsetAsync(z2, 0, (size_t)BB * K2P * 2, stream);
    hipMemsetAsync(h1pad, 0, (size_t)BB * HP * 2, stream);
    hipMemsetAsync(h2pad, 0, (size_t)BB * HP * 2, stream);

    prep_w1p<<<4096, 256, 0, stream>>>(Wih1, Whh1, w1cat);
    prep_w2p<<<dim3(27, G4P), 256, 0, stream>>>(Wih2, Whh2, w2cat);
    prep_outwp<<<dim3(4, DP), 256, 0, stream>>>(outW, outwb);
    prep_cvt<<<1024, 256, 0, stream>>>(layW, laywb, (size_t)HID * HID);
    prep_addv<<<16, 256, 0, stream>>>(bih1, bhh1, bias1, G4);
    prep_addv<<<16, 256, 0, stream>>>(bih2, bhh2, bias2, G4);
    init_vec<<<1000, 256, 0, stream>>>(h1, h1pad, HP);
    init_vec<<<1000, 256, 0, stream>>>(h2, h2pad, HP);
    init_vec<<<1000, 256, 0, stream>>>(h2, z2 + Z2_H2, K2P);
    hipMemcpyAsync(c1, c1in, (size_t)BB * HID * 4, hipMemcpyDeviceToDevice, stream);
    hipMemcpyAsync(c2, c2in, (size_t)BB * HID * 4, hipMemcpyDeviceToDevice, stream);

    // input projection -> xp[t][b][0:1000] (bf16, stride 1024, pads stay zero)
    gemm_nt<1, 1><<<dim3(16, (BB * TT) / 64, 1), 256, 0, stream>>>(
        x, HID, laywb, HID, layb, xp, 0, HP, BB * TT, HID, HID);

    for (int t = 0; t < TT; ++t) {
        // gates1 = [xp_t | h1] @ w1cat^T   (2 M-tiles x 32 N-tiles x K-split 4)
        gemm_s128<<<dim3(32, 2, 4), 512, 0, stream>>>(
            xp + (size_t)t * BB * HP, h1pad - HP, 1024, HP, w1cat, K1P, gbuf, GPART, G4P, K1P / 32);
        lstm_ewN<4><<<1000, 256, 0, stream>>>(gbuf, GPART, bias1, c1, z2 + Z2_H1, K2P, h1pad, HP);

        // gates2 = z2 @ w2cat^T   (2 M-tiles x 32 N-tiles x K-split 8 = 512 blocks, 2/CU)
        gemm_s128<<<dim3(32, 2, 8), 512, 0, stream>>>(
            z2, z2, 0, K2P, w2cat, K2P, gbuf, GPART, G4P, K2P / 32);
        lstm_ewN<8><<<1000, 256, 0, stream>>>(gbuf, GPART, bias2, c2, z2 + Z2_H2, K2P, h2pad, HP);

        // logits(t) + batch-softmax fused -> out, z2.prev
        logits_sm<<<76, 512, 0, stream>>>(h2pad, outwb, outb, out, z2, t);
    }
}